// Round 4
// baseline (5507.303 us; speedup 1.0000x reference)
//
#include <hip/hip_runtime.h>
#include <stdint.h>

typedef __bf16 bf16x8 __attribute__((ext_vector_type(8)));
typedef float floatx4 __attribute__((ext_vector_type(4)));
typedef unsigned long long u64x2 __attribute__((ext_vector_type(2)));

#define T_STEPS 512
#define BATCH   64
#define HDIM    512
#define NGATE   1024   // 2*H
#define IDIM    512
#define RBLOCKS 32     // recurrent blocks, 16 cols each

__device__ __forceinline__ unsigned short f2bf(float f) {
  unsigned int u = __builtin_bit_cast(unsigned int, f);
  u += 0x7fffu + ((u >> 16) & 1u);
  return (unsigned short)(u >> 16);
}
__device__ __forceinline__ float bf2f(unsigned short s) {
  unsigned int u = ((unsigned int)s) << 16;
  return __builtin_bit_cast(float, u);
}

// ---------------- fp32 -> bf16 hi + lo residual ----------------
__global__ void cvt_split_kernel(const float4* __restrict__ src,
                                 ushort4* __restrict__ hi, ushort4* __restrict__ lo, int n4) {
  int i = blockIdx.x * blockDim.x + threadIdx.x;
  if (i >= n4) return;
  float4 v = src[i];
  ushort4 h, l;
  h.x = f2bf(v.x); l.x = f2bf(v.x - bf2f(h.x));
  h.y = f2bf(v.y); l.y = f2bf(v.y - bf2f(h.y));
  h.z = f2bf(v.z); l.z = f2bf(v.z - bf2f(h.z));
  h.w = f2bf(v.w); l.w = f2bf(v.w - bf2f(h.w));
  hi[i] = h; lo[i] = l;
}

// biasc[i] = bih[i] + (i < H ? bhh[i] : 0)
// f-gate bias is additive (fold both); n-gate b_hh goes INSIDE f*(.) in the step.
__global__ void bias_kernel(const float* __restrict__ a, const float* __restrict__ b,
                            float* __restrict__ c, int n) {
  int i = blockIdx.x * blockDim.x + threadIdx.x;
  if (i < n) c[i] = a[i] + (i < HDIM ? b[i] : 0.0f);
}

// ---------------- async global->LDS 16B ----------------
__device__ __forceinline__ void g2l16(const void* g, void* l) {
  __builtin_amdgcn_global_load_lds(
      (const __attribute__((address_space(1))) unsigned int*)g,
      (__attribute__((address_space(3))) unsigned int*)l, 16, 0, 0);
}

// ---------------- Gi GEMM, split-split: C = (Ahi+Alo)(Bhi+Blo)^T + bias ----------------
// 3-term: AhBh + AlBh + AhBl. 128x128 tile, BK=32, 4 waves. C fp32.
__global__ __launch_bounds__(256) void gemm_bt(
    const unsigned short* __restrict__ Ahi,  // [M x K] bf16
    const unsigned short* __restrict__ Alo,  // [M x K] bf16
    const unsigned short* __restrict__ Bhi,  // [N x K] bf16
    const unsigned short* __restrict__ Blo,  // [N x K] bf16
    const float* __restrict__ bias,          // [N]
    float* __restrict__ C,                   // [M x N] fp32
    int M, int N, int K) {
  __shared__ unsigned short Ahs[128 * 32];
  __shared__ unsigned short Als[128 * 32];
  __shared__ unsigned short Bhs[128 * 32];
  __shared__ unsigned short Bls[128 * 32];
  const int tid  = threadIdx.x;
  const int w    = tid >> 6, lane = tid & 63;
  const int m16  = lane & 15, quad = lane >> 4;
  const int gn   = N >> 7;
  const int by   = blockIdx.x / gn, bx = blockIdx.x % gn;
  const int wm   = w & 1, wn = w >> 1;

  const int rr = lane >> 2;   // 0..15 (row within 16-row stripe)
  const int cc = lane & 3;    // 16B chunk within 32-col row
  const size_t ro0 = (size_t)((w*2+0)*16 + rr) * K + cc*8;
  const size_t ro1 = (size_t)((w*2+1)*16 + rr) * K + cc*8;
  const unsigned short* Ah0 = Ahi + (size_t)by*128*K + ro0;
  const unsigned short* Ah1 = Ahi + (size_t)by*128*K + ro1;
  const unsigned short* Al0 = Alo + (size_t)by*128*K + ro0;
  const unsigned short* Al1 = Alo + (size_t)by*128*K + ro1;
  const unsigned short* Bh0 = Bhi + (size_t)bx*128*K + ro0;
  const unsigned short* Bh1 = Bhi + (size_t)bx*128*K + ro1;
  const unsigned short* Bl0 = Blo + (size_t)bx*128*K + ro0;
  const unsigned short* Bl1 = Blo + (size_t)bx*128*K + ro1;

  floatx4 acc[4][4] = {};

  for (int k0 = 0; k0 < K; k0 += 32) {
    g2l16(Ah0 + k0, &Ahs[(w*2+0)*512]);
    g2l16(Ah1 + k0, &Ahs[(w*2+1)*512]);
    g2l16(Al0 + k0, &Als[(w*2+0)*512]);
    g2l16(Al1 + k0, &Als[(w*2+1)*512]);
    g2l16(Bh0 + k0, &Bhs[(w*2+0)*512]);
    g2l16(Bh1 + k0, &Bhs[(w*2+1)*512]);
    g2l16(Bl0 + k0, &Bls[(w*2+0)*512]);
    g2l16(Bl1 + k0, &Bls[(w*2+1)*512]);
    __syncthreads();

    bf16x8 ah[4], al[4], bh[4], bl[4];
#pragma unroll
    for (int mt = 0; mt < 4; ++mt) {
      ah[mt] = *(const bf16x8*)&Ahs[(wm*64 + mt*16 + m16)*32 + quad*8];
      al[mt] = *(const bf16x8*)&Als[(wm*64 + mt*16 + m16)*32 + quad*8];
    }
#pragma unroll
    for (int nt = 0; nt < 4; ++nt) {
      bh[nt] = *(const bf16x8*)&Bhs[(wn*64 + nt*16 + m16)*32 + quad*8];
      bl[nt] = *(const bf16x8*)&Bls[(wn*64 + nt*16 + m16)*32 + quad*8];
    }
#pragma unroll
    for (int mt = 0; mt < 4; ++mt)
#pragma unroll
      for (int nt = 0; nt < 4; ++nt) {
        acc[mt][nt] = __builtin_amdgcn_mfma_f32_16x16x32_bf16(ah[mt], bh[nt], acc[mt][nt], 0, 0, 0);
        acc[mt][nt] = __builtin_amdgcn_mfma_f32_16x16x32_bf16(al[mt], bh[nt], acc[mt][nt], 0, 0, 0);
        acc[mt][nt] = __builtin_amdgcn_mfma_f32_16x16x32_bf16(ah[mt], bl[nt], acc[mt][nt], 0, 0, 0);
      }
    __syncthreads();
  }

  // epilogue: C layout col=lane&15, row=quad*4+r
#pragma unroll
  for (int nt = 0; nt < 4; ++nt) {
    int col = bx*128 + wn*64 + nt*16 + m16;
    float bv = bias[col];
#pragma unroll
    for (int mt = 0; mt < 4; ++mt) {
      int row0 = by*128 + wm*64 + mt*16 + quad*4;
#pragma unroll
      for (int r = 0; r < 4; ++r)
        C[(size_t)(row0 + r)*N + col] = acc[mt][nt][r] + bv;
    }
  }
}

// ---------------- persistent recurrent kernel (split precision) ----------------
// 32 blocks x 256 threads. Block k owns output cols [16k,16k+16).
// xn = gi_n + f * (h·W_n^T + b_hh_n)   <-- b_hh_n INSIDE the gate product
__global__ __launch_bounds__(256, 1) void mgu_recur(
    const float* __restrict__ Gi,            // [T*B, 1024] fp32 (f: both biases; n: b_ih only)
    const unsigned short* __restrict__ Whi,  // [1024, 512] bf16 hi
    const unsigned short* __restrict__ Wlo,  // [1024, 512] bf16 lo
    const float* __restrict__ bhh,           // [1024] fp32 (n-half used)
    unsigned short* __restrict__ hhi,        // [2][64][512] bf16 hi (parity dbuf)
    unsigned short* __restrict__ hlo,        // [2][64][512] bf16 lo
    unsigned int* __restrict__ cnt,          // arrival counter (zeroed by memset)
    float* __restrict__ out) {               // [T*B, 512] fp32
  const int tid  = threadIdx.x;
  const int w    = tid >> 6, lane = tid & 63;
  const int m16  = lane & 15, quad = lane >> 4;
  const int j0   = blockIdx.x * 16;

  __shared__ float          hf_lds[64][16];
  __shared__ unsigned short hh_lds[64][16];
  __shared__ unsigned short hl_lds[64][16];

  const float bnb = bhh[512 + j0 + m16];   // b_hh_n for this lane's output column

  // W_hh fragments in registers: B[n=lane&15][k=quad*8+j]
  bf16x8 wfh[16], wnh[16], wfl[16], wnl[16];
#pragma unroll
  for (int kk = 0; kk < 16; ++kk) {
    size_t of = (size_t)(j0 + m16)       * 512 + kk*32 + quad*8;
    size_t on = (size_t)(512 + j0 + m16) * 512 + kk*32 + quad*8;
    wfh[kk] = *(const bf16x8*)&Whi[of];
    wnh[kk] = *(const bf16x8*)&Whi[on];
    wfl[kk] = *(const bf16x8*)&Wlo[of];
    wnl[kk] = *(const bf16x8*)&Wlo[on];
  }

#pragma unroll 1
  for (int t = 0; t < T_STEPS; ++t) {
    // Gi prefetch (fp32, independent of h)
    float gif[4], gin[4];
#pragma unroll
    for (int r = 0; r < 4; ++r) {
      size_t row = (size_t)t*64 + w*16 + quad*4 + r;
      gif[r] = Gi[row*1024 + j0 + m16];
      gin[r] = Gi[row*1024 + 512 + j0 + m16];
    }

    floatx4 accf0 = {}, accf1 = {}, accf2 = {};
    floatx4 accn0 = {}, accn1 = {}, accn2 = {};

    if (t > 0) {
      if (tid == 0) {
        const unsigned int target = 32u * (unsigned int)t;
        while (__hip_atomic_load(cnt, __ATOMIC_ACQUIRE, __HIP_MEMORY_SCOPE_AGENT) < target)
          __builtin_amdgcn_s_sleep(1);
      }
      __syncthreads();

      const size_t pb = (size_t)((t-1)&1) * BATCH * HDIM;
      const unsigned long long* hbh = (const unsigned long long*)(hhi + pb);
      const unsigned long long* hbl = (const unsigned long long*)(hlo + pb);
      const int arow = w*16 + m16;
      u64x2 avh[16], avl[16];
#pragma unroll
      for (int kk = 0; kk < 16; ++kk) {
        size_t o = (size_t)arow*128 + kk*8 + quad*2;
        avh[kk].x = __hip_atomic_load(hbh + o,     __ATOMIC_RELAXED, __HIP_MEMORY_SCOPE_AGENT);
        avh[kk].y = __hip_atomic_load(hbh + o + 1, __ATOMIC_RELAXED, __HIP_MEMORY_SCOPE_AGENT);
        avl[kk].x = __hip_atomic_load(hbl + o,     __ATOMIC_RELAXED, __HIP_MEMORY_SCOPE_AGENT);
        avl[kk].y = __hip_atomic_load(hbl + o + 1, __ATOMIC_RELAXED, __HIP_MEMORY_SCOPE_AGENT);
      }
#pragma unroll
      for (int kk = 0; kk < 16; ++kk) {
        bf16x8 ah = __builtin_bit_cast(bf16x8, avh[kk]);
        bf16x8 al = __builtin_bit_cast(bf16x8, avl[kk]);
        accf0 = __builtin_amdgcn_mfma_f32_16x16x32_bf16(ah, wfh[kk], accf0, 0, 0, 0);
        accf1 = __builtin_amdgcn_mfma_f32_16x16x32_bf16(al, wfh[kk], accf1, 0, 0, 0);
        accf2 = __builtin_amdgcn_mfma_f32_16x16x32_bf16(ah, wfl[kk], accf2, 0, 0, 0);
        accn0 = __builtin_amdgcn_mfma_f32_16x16x32_bf16(ah, wnh[kk], accn0, 0, 0, 0);
        accn1 = __builtin_amdgcn_mfma_f32_16x16x32_bf16(al, wnh[kk], accn1, 0, 0, 0);
        accn2 = __builtin_amdgcn_mfma_f32_16x16x32_bf16(ah, wnl[kk], accn2, 0, 0, 0);
      }
    }

    // gates + nonlinearity (fp32), h split into hi/lo bf16
#pragma unroll
    for (int r = 0; r < 4; ++r) {
      float xf = gif[r] + (accf0[r] + accf1[r] + accf2[r]);
      float f  = 1.0f / (1.0f + __expf(-xf));
      float xn = gin[r] + f * (accn0[r] + accn1[r] + accn2[r] + bnb);
      float e  = __expf(-2.0f * xn);
      float h  = (1.0f - e) / (1.0f + e);    // tanh
      int brow = w*16 + quad*4 + r;
      unsigned short hh = f2bf(h);
      hf_lds[brow][m16] = h;
      hh_lds[brow][m16] = hh;
      hl_lds[brow][m16] = f2bf(h - bf2f(hh));
    }
    __syncthreads();

    // coalesced writeback via LDS bounce: 256 threads = 64 rows x 4 chunks
    {
      int row = tid >> 2, ch = tid & 3;
      float4 vo = *(const float4*)&hf_lds[row][ch*4];
      *(float4*)&out[((size_t)t*64 + row)*512 + j0 + ch*4] = vo;
      size_t po = (size_t)(t&1)*BATCH*HDIM + row*512 + j0 + ch*4;
      unsigned long long vh = *(const unsigned long long*)&hh_lds[row][ch*4];
      unsigned long long vl = *(const unsigned long long*)&hl_lds[row][ch*4];
      __hip_atomic_store((unsigned long long*)(hhi + po), vh,
                         __ATOMIC_RELAXED, __HIP_MEMORY_SCOPE_AGENT);
      __hip_atomic_store((unsigned long long*)(hlo + po), vl,
                         __ATOMIC_RELAXED, __HIP_MEMORY_SCOPE_AGENT);
    }
    __syncthreads();

    if (tid == 0)
      __hip_atomic_fetch_add(cnt, 1u, __ATOMIC_RELEASE, __HIP_MEMORY_SCOPE_AGENT);
  }
}

// ---------------- launch ----------------
extern "C" void kernel_launch(void* const* d_in, const int* in_sizes, int n_in,
                              void* d_out, int out_size, void* d_ws, size_t ws_size,
                              hipStream_t stream) {
  (void)in_sizes; (void)n_in; (void)out_size; (void)ws_size;
  const float* X   = (const float*)d_in[0];   // [512,64,512]
  const float* Wih = (const float*)d_in[1];   // [1024,512]
  const float* Whh = (const float*)d_in[2];   // [1024,512]
  const float* bih = (const float*)d_in[3];   // [1024]
  const float* bhh = (const float*)d_in[4];   // [1024]
  float* out = (float*)d_out;

  const int TB = T_STEPS * BATCH;  // 32768

  // workspace layout (~207 MB)
  unsigned short* Xhi    = (unsigned short*)d_ws;                    // TB*IDIM bf16
  unsigned short* Xlo    = Xhi   + (size_t)TB * IDIM;
  unsigned short* WihHi  = Xlo   + (size_t)TB * IDIM;                // NGATE*IDIM
  unsigned short* WihLo  = WihHi + (size_t)NGATE * IDIM;
  unsigned short* WhhHi  = WihLo + (size_t)NGATE * IDIM;             // NGATE*HDIM
  unsigned short* WhhLo  = WhhHi + (size_t)NGATE * HDIM;
  float*          biasc  = (float*)(WhhLo + (size_t)NGATE * HDIM);   // NGATE
  float*          Gi     = biasc + NGATE;                            // TB*NGATE fp32
  unsigned short* hhi    = (unsigned short*)(Gi + (size_t)TB * NGATE); // 2*B*H
  unsigned short* hlo    = hhi + 2*BATCH*HDIM;
  unsigned int*   cnt    = (unsigned int*)(hlo + 2*BATCH*HDIM);

  hipMemsetAsync(cnt, 0, 64, stream);

  int n4;
  n4 = TB * IDIM / 4;
  cvt_split_kernel<<<n4/256, 256, 0, stream>>>((const float4*)X, (ushort4*)Xhi, (ushort4*)Xlo, n4);
  n4 = NGATE * IDIM / 4;
  cvt_split_kernel<<<n4/256, 256, 0, stream>>>((const float4*)Wih, (ushort4*)WihHi, (ushort4*)WihLo, n4);
  n4 = NGATE * HDIM / 4;
  cvt_split_kernel<<<n4/256, 256, 0, stream>>>((const float4*)Whh, (ushort4*)WhhHi, (ushort4*)WhhLo, n4);
  bias_kernel<<<4, 256, 0, stream>>>(bih, bhh, biasc, NGATE);

  gemm_bt<<<(TB/128)*(NGATE/128), 256, 0, stream>>>(Xhi, Xlo, WihHi, WihLo, biasc, Gi, TB, NGATE, IDIM);

  mgu_recur<<<RBLOCKS, 256, 0, stream>>>(Gi, WhhHi, WhhLo, bhh, hhi, hlo, cnt, out);
}

// Round 6
// 4714.290 us; speedup vs baseline: 1.1682x; 1.1682x over previous
//
#include <hip/hip_runtime.h>
#include <stdint.h>

typedef __bf16 bf16x8 __attribute__((ext_vector_type(8)));
typedef float floatx4 __attribute__((ext_vector_type(4)));
typedef unsigned long long u64x2 __attribute__((ext_vector_type(2)));

#define T_STEPS 512
#define BATCH   64
#define HDIM    512
#define NGATE   1024   // 2*H
#define IDIM    512
#define RBLOCKS 32     // recurrent blocks, 16 cols each

__device__ __forceinline__ unsigned short f2bf(float f) {
  unsigned int u = __builtin_bit_cast(unsigned int, f);
  u += 0x7fffu + ((u >> 16) & 1u);
  return (unsigned short)(u >> 16);
}
__device__ __forceinline__ float bf2f(unsigned short s) {
  unsigned int u = ((unsigned int)s) << 16;
  return __builtin_bit_cast(float, u);
}

// ---------------- fp32 -> bf16 hi + lo residual ----------------
__global__ void cvt_split_kernel(const float4* __restrict__ src,
                                 ushort4* __restrict__ hi, ushort4* __restrict__ lo, int n4) {
  int i = blockIdx.x * blockDim.x + threadIdx.x;
  if (i >= n4) return;
  float4 v = src[i];
  ushort4 h, l;
  h.x = f2bf(v.x); l.x = f2bf(v.x - bf2f(h.x));
  h.y = f2bf(v.y); l.y = f2bf(v.y - bf2f(h.y));
  h.z = f2bf(v.z); l.z = f2bf(v.z - bf2f(h.z));
  h.w = f2bf(v.w); l.w = f2bf(v.w - bf2f(h.w));
  hi[i] = h; lo[i] = l;
}

// biasc[i] = bih[i] + (i < H ? bhh[i] : 0)
// f-gate bias is additive (fold both); n-gate b_hh goes INSIDE f*(.) in the step.
__global__ void bias_kernel(const float* __restrict__ a, const float* __restrict__ b,
                            float* __restrict__ c, int n) {
  int i = blockIdx.x * blockDim.x + threadIdx.x;
  if (i < n) c[i] = a[i] + (i < HDIM ? b[i] : 0.0f);
}

// ---------------- async global->LDS 16B ----------------
__device__ __forceinline__ void g2l16(const void* g, void* l) {
  __builtin_amdgcn_global_load_lds(
      (const __attribute__((address_space(1))) unsigned int*)g,
      (__attribute__((address_space(3))) unsigned int*)l, 16, 0, 0);
}

// ---------------- Gi GEMM, split-split: C = (Ahi+Alo)(Bhi+Blo)^T + bias ----------------
// 3-term: AhBh + AlBh + AhBl. 128x128 tile, BK=32, 4 waves. C fp32.
__global__ __launch_bounds__(256) void gemm_bt(
    const unsigned short* __restrict__ Ahi,  // [M x K] bf16
    const unsigned short* __restrict__ Alo,  // [M x K] bf16
    const unsigned short* __restrict__ Bhi,  // [N x K] bf16
    const unsigned short* __restrict__ Blo,  // [N x K] bf16
    const float* __restrict__ bias,          // [N]
    float* __restrict__ C,                   // [M x N] fp32
    int M, int N, int K) {
  __shared__ unsigned short Ahs[128 * 32];
  __shared__ unsigned short Als[128 * 32];
  __shared__ unsigned short Bhs[128 * 32];
  __shared__ unsigned short Bls[128 * 32];
  const int tid  = threadIdx.x;
  const int w    = tid >> 6, lane = tid & 63;
  const int m16  = lane & 15, quad = lane >> 4;
  const int gn   = N >> 7;
  const int by   = blockIdx.x / gn, bx = blockIdx.x % gn;
  const int wm   = w & 1, wn = w >> 1;

  const int rr = lane >> 2;   // 0..15 (row within 16-row stripe)
  const int cc = lane & 3;    // 16B chunk within 32-col row
  const size_t ro0 = (size_t)((w*2+0)*16 + rr) * K + cc*8;
  const size_t ro1 = (size_t)((w*2+1)*16 + rr) * K + cc*8;
  const unsigned short* Ah0 = Ahi + (size_t)by*128*K + ro0;
  const unsigned short* Ah1 = Ahi + (size_t)by*128*K + ro1;
  const unsigned short* Al0 = Alo + (size_t)by*128*K + ro0;
  const unsigned short* Al1 = Alo + (size_t)by*128*K + ro1;
  const unsigned short* Bh0 = Bhi + (size_t)bx*128*K + ro0;
  const unsigned short* Bh1 = Bhi + (size_t)bx*128*K + ro1;
  const unsigned short* Bl0 = Blo + (size_t)bx*128*K + ro0;
  const unsigned short* Bl1 = Blo + (size_t)bx*128*K + ro1;

  floatx4 acc[4][4] = {};

  for (int k0 = 0; k0 < K; k0 += 32) {
    g2l16(Ah0 + k0, &Ahs[(w*2+0)*512]);
    g2l16(Ah1 + k0, &Ahs[(w*2+1)*512]);
    g2l16(Al0 + k0, &Als[(w*2+0)*512]);
    g2l16(Al1 + k0, &Als[(w*2+1)*512]);
    g2l16(Bh0 + k0, &Bhs[(w*2+0)*512]);
    g2l16(Bh1 + k0, &Bhs[(w*2+1)*512]);
    g2l16(Bl0 + k0, &Bls[(w*2+0)*512]);
    g2l16(Bl1 + k0, &Bls[(w*2+1)*512]);
    __syncthreads();

    bf16x8 ah[4], al[4], bh[4], bl[4];
#pragma unroll
    for (int mt = 0; mt < 4; ++mt) {
      ah[mt] = *(const bf16x8*)&Ahs[(wm*64 + mt*16 + m16)*32 + quad*8];
      al[mt] = *(const bf16x8*)&Als[(wm*64 + mt*16 + m16)*32 + quad*8];
    }
#pragma unroll
    for (int nt = 0; nt < 4; ++nt) {
      bh[nt] = *(const bf16x8*)&Bhs[(wn*64 + nt*16 + m16)*32 + quad*8];
      bl[nt] = *(const bf16x8*)&Bls[(wn*64 + nt*16 + m16)*32 + quad*8];
    }
#pragma unroll
    for (int mt = 0; mt < 4; ++mt)
#pragma unroll
      for (int nt = 0; nt < 4; ++nt) {
        acc[mt][nt] = __builtin_amdgcn_mfma_f32_16x16x32_bf16(ah[mt], bh[nt], acc[mt][nt], 0, 0, 0);
        acc[mt][nt] = __builtin_amdgcn_mfma_f32_16x16x32_bf16(al[mt], bh[nt], acc[mt][nt], 0, 0, 0);
        acc[mt][nt] = __builtin_amdgcn_mfma_f32_16x16x32_bf16(ah[mt], bl[nt], acc[mt][nt], 0, 0, 0);
      }
    __syncthreads();
  }

  // epilogue: C layout col=lane&15, row=quad*4+r
#pragma unroll
  for (int nt = 0; nt < 4; ++nt) {
    int col = bx*128 + wn*64 + nt*16 + m16;
    float bv = bias[col];
#pragma unroll
    for (int mt = 0; mt < 4; ++mt) {
      int row0 = by*128 + wm*64 + mt*16 + quad*4;
#pragma unroll
      for (int r = 0; r < 4; ++r)
        C[(size_t)(row0 + r)*N + col] = acc[mt][nt][r] + bv;
    }
  }
}

// ---------------- persistent recurrent kernel (split precision) ----------------
// 32 blocks x 256 threads. Block k owns output cols [16k,16k+16).
// Sync: per-block flag words (128B apart), RELAXED agent atomics only.
// Release = __syncthreads' vmcnt(0) drain before the flag store (stores are
// sc1/coherence-point ops, so completion == global visibility).
// Acquire = relaxed sc1 poll load always reads the coherence point.
__global__ __launch_bounds__(256, 1) void mgu_recur(
    const float* __restrict__ Gi,            // [T*B, 1024] fp32 (f: both biases; n: b_ih only)
    const unsigned short* __restrict__ Whi,  // [1024, 512] bf16 hi
    const unsigned short* __restrict__ Wlo,  // [1024, 512] bf16 lo
    const float* __restrict__ bhh,           // [1024] fp32 (n-half used)
    unsigned short* __restrict__ hhi,        // [2][64][512] bf16 hi (parity dbuf)
    unsigned short* __restrict__ hlo,        // [2][64][512] bf16 lo
    unsigned int* __restrict__ flags,        // 32 words, stride 32 (zeroed by memset)
    float* __restrict__ out) {               // [T*B, 512] fp32
  const int tid  = threadIdx.x;
  const int w    = tid >> 6, lane = tid & 63;
  const int m16  = lane & 15, quad = lane >> 4;
  const int j0   = blockIdx.x * 16;

  __shared__ float          hf_lds[64][16];
  __shared__ unsigned short hh_lds[64][16];
  __shared__ unsigned short hl_lds[64][16];

  const float bnb = bhh[512 + j0 + m16];   // b_hh_n for this lane's output column

  // W_hh fragments in registers: B[n=lane&15][k=quad*8+j]
  bf16x8 wfh[16], wnh[16], wfl[16], wnl[16];
#pragma unroll
  for (int kk = 0; kk < 16; ++kk) {
    size_t of = (size_t)(j0 + m16)       * 512 + kk*32 + quad*8;
    size_t on = (size_t)(512 + j0 + m16) * 512 + kk*32 + quad*8;
    wfh[kk] = *(const bf16x8*)&Whi[of];
    wnh[kk] = *(const bf16x8*)&Whi[on];
    wfl[kk] = *(const bf16x8*)&Wlo[of];
    wnl[kk] = *(const bf16x8*)&Wlo[on];
  }

  unsigned int* myflag = flags + blockIdx.x * 32;
  const unsigned int* pollflag = flags + (lane & 31) * 32;

#pragma unroll 1
  for (int t = 0; t < T_STEPS; ++t) {
    // Gi prefetch (fp32, independent of h) — overlaps the flag wait
    float gif[4], gin[4];
#pragma unroll
    for (int r = 0; r < 4; ++r) {
      size_t row = (size_t)t*64 + w*16 + quad*4 + r;
      gif[r] = Gi[row*1024 + j0 + m16];
      gin[r] = Gi[row*1024 + 512 + j0 + m16];
    }

    floatx4 accf0 = {}, accf1 = {}, accf2 = {};
    floatx4 accn0 = {}, accn1 = {}, accn2 = {};

    if (t > 0) {
      // lane-parallel poll: wave 0, lane i watches flags[i&31]; no fences
      if (w == 0) {
        while (__hip_atomic_load(pollflag, __ATOMIC_RELAXED, __HIP_MEMORY_SCOPE_AGENT)
               < (unsigned int)t)
          __builtin_amdgcn_s_sleep(1);
      }
      __syncthreads();

      const size_t pb = (size_t)((t-1)&1) * BATCH * HDIM;
      const unsigned long long* hbh = (const unsigned long long*)(hhi + pb);
      const unsigned long long* hbl = (const unsigned long long*)(hlo + pb);
      const int arow = w*16 + m16;
      u64x2 avh[16], avl[16];
#pragma unroll
      for (int kk = 0; kk < 16; ++kk) {
        size_t o = (size_t)arow*128 + kk*8 + quad*2;
        avh[kk].x = __hip_atomic_load(hbh + o,     __ATOMIC_RELAXED, __HIP_MEMORY_SCOPE_AGENT);
        avh[kk].y = __hip_atomic_load(hbh + o + 1, __ATOMIC_RELAXED, __HIP_MEMORY_SCOPE_AGENT);
        avl[kk].x = __hip_atomic_load(hbl + o,     __ATOMIC_RELAXED, __HIP_MEMORY_SCOPE_AGENT);
        avl[kk].y = __hip_atomic_load(hbl + o + 1, __ATOMIC_RELAXED, __HIP_MEMORY_SCOPE_AGENT);
      }
#pragma unroll
      for (int kk = 0; kk < 16; ++kk) {
        bf16x8 ah = __builtin_bit_cast(bf16x8, avh[kk]);
        bf16x8 al = __builtin_bit_cast(bf16x8, avl[kk]);
        accf0 = __builtin_amdgcn_mfma_f32_16x16x32_bf16(ah, wfh[kk], accf0, 0, 0, 0);
        accf1 = __builtin_amdgcn_mfma_f32_16x16x32_bf16(al, wfh[kk], accf1, 0, 0, 0);
        accf2 = __builtin_amdgcn_mfma_f32_16x16x32_bf16(ah, wfl[kk], accf2, 0, 0, 0);
        accn0 = __builtin_amdgcn_mfma_f32_16x16x32_bf16(ah, wnh[kk], accn0, 0, 0, 0);
        accn1 = __builtin_amdgcn_mfma_f32_16x16x32_bf16(al, wnh[kk], accn1, 0, 0, 0);
        accn2 = __builtin_amdgcn_mfma_f32_16x16x32_bf16(ah, wnl[kk], accn2, 0, 0, 0);
      }
    }

    // gates + nonlinearity (fp32), h split into hi/lo bf16
#pragma unroll
    for (int r = 0; r < 4; ++r) {
      float xf = gif[r] + (accf0[r] + accf1[r] + accf2[r]);
      float f  = 1.0f / (1.0f + __expf(-xf));
      float xn = gin[r] + f * (accn0[r] + accn1[r] + accn2[r] + bnb);
      float e  = __expf(-2.0f * xn);
      float h  = (1.0f - e) / (1.0f + e);    // tanh
      int brow = w*16 + quad*4 + r;
      unsigned short hh = f2bf(h);
      hf_lds[brow][m16] = h;
      hh_lds[brow][m16] = hh;
      hl_lds[brow][m16] = f2bf(h - bf2f(hh));
    }
    __syncthreads();

    // coalesced writeback via LDS bounce: 256 threads = 64 rows x 4 chunks
    {
      int row = tid >> 2, ch = tid & 3;
      floatx4 vo = *(const floatx4*)&hf_lds[row][ch*4];
      __builtin_nontemporal_store(vo,
          (floatx4*)&out[((size_t)t*64 + row)*512 + j0 + ch*4]);
      size_t po = (size_t)(t&1)*BATCH*HDIM + row*512 + j0 + ch*4;
      unsigned long long vh = *(const unsigned long long*)&hh_lds[row][ch*4];
      unsigned long long vl = *(const unsigned long long*)&hl_lds[row][ch*4];
      __hip_atomic_store((unsigned long long*)(hhi + po), vh,
                         __ATOMIC_RELAXED, __HIP_MEMORY_SCOPE_AGENT);
      __hip_atomic_store((unsigned long long*)(hlo + po), vl,
                         __ATOMIC_RELAXED, __HIP_MEMORY_SCOPE_AGENT);
    }
    __syncthreads();   // vmcnt(0) drain: h stores are at the coherence point

    if (tid == 0)
      __hip_atomic_store(myflag, (unsigned int)(t + 1),
                         __ATOMIC_RELAXED, __HIP_MEMORY_SCOPE_AGENT);
  }
}

// ---------------- launch ----------------
extern "C" void kernel_launch(void* const* d_in, const int* in_sizes, int n_in,
                              void* d_out, int out_size, void* d_ws, size_t ws_size,
                              hipStream_t stream) {
  (void)in_sizes; (void)n_in; (void)out_size; (void)ws_size;
  const float* X   = (const float*)d_in[0];   // [512,64,512]
  const float* Wih = (const float*)d_in[1];   // [1024,512]
  const float* Whh = (const float*)d_in[2];   // [1024,512]
  const float* bih = (const float*)d_in[3];   // [1024]
  const float* bhh = (const float*)d_in[4];   // [1024]
  float* out = (float*)d_out;

  const int TB = T_STEPS * BATCH;  // 32768

  // workspace layout (~207 MB)
  unsigned short* Xhi    = (unsigned short*)d_ws;                    // TB*IDIM bf16
  unsigned short* Xlo    = Xhi   + (size_t)TB * IDIM;
  unsigned short* WihHi  = Xlo   + (size_t)TB * IDIM;                // NGATE*IDIM
  unsigned short* WihLo  = WihHi + (size_t)NGATE * IDIM;
  unsigned short* WhhHi  = WihLo + (size_t)NGATE * IDIM;             // NGATE*HDIM
  unsigned short* WhhLo  = WhhHi + (size_t)NGATE * HDIM;
  float*          biasc  = (float*)(WhhLo + (size_t)NGATE * HDIM);   // NGATE
  float*          Gi     = biasc + NGATE;                            // TB*NGATE fp32
  unsigned short* hhi    = (unsigned short*)(Gi + (size_t)TB * NGATE); // 2*B*H
  unsigned short* hlo    = hhi + 2*BATCH*HDIM;
  unsigned int*   flags  = (unsigned int*)(hlo + 2*BATCH*HDIM);      // 32 x stride-32 u32

  (void)hipMemsetAsync(flags, 0, RBLOCKS * 32 * sizeof(unsigned int), stream);

  int n4;
  n4 = TB * IDIM / 4;
  cvt_split_kernel<<<n4/256, 256, 0, stream>>>((const float4*)X, (ushort4*)Xhi, (ushort4*)Xlo, n4);
  n4 = NGATE * IDIM / 4;
  cvt_split_kernel<<<n4/256, 256, 0, stream>>>((const float4*)Wih, (ushort4*)WihHi, (ushort4*)WihLo, n4);
  n4 = NGATE * HDIM / 4;
  cvt_split_kernel<<<n4/256, 256, 0, stream>>>((const float4*)Whh, (ushort4*)WhhHi, (ushort4*)WhhLo, n4);
  bias_kernel<<<4, 256, 0, stream>>>(bih, bhh, biasc, NGATE);

  gemm_bt<<<(TB/128)*(NGATE/128), 256, 0, stream>>>(Xhi, Xlo, WihHi, WihLo, biasc, Gi, TB, NGATE, IDIM);

  mgu_recur<<<RBLOCKS, 256, 0, stream>>>(Gi, WhhHi, WhhLo, bhh, hhi, hlo, flags, out);
}